// Round 7
// baseline (427.489 us; speedup 1.0000x reference)
//
#include <hip/hip_runtime.h>

#define D 4096
#define RANK 1024
#define UELEMS 4194304ULL   // D*RANK
#define NTOT 16777216ULL    // 4^12 = D*D
#define QSCALE 16000.0f

typedef __attribute__((ext_vector_type(4))) int i32x4;

__device__ float g_inv_tr[1];
__device__ float g_scale[D];
__device__ float g_mdre[16];   // M-dagger tables: M†[s][i][j] = conj(M[s][j][i])
__device__ float g_mdim[16];

#define MFMA_I8 __builtin_amdgcn_mfma_i32_16x16x64_i8

// ---------------------------------------------------------------------------
// i8 split quantization of W = [Ur | Ui] with per-row scale (verified r6).
// r17: writes ONLY the k-major copy W2[p][k16][col][16B], p in {Ur-hi, Ur-lo,
// Ui-hi, Ui-lo} (the row-major Wh/Wl planes are no longer read by anyone).
// ---------------------------------------------------------------------------
__global__ __launch_bounds__(256) void convert_w_i8(const float* __restrict__ P,
                                                    const float* __restrict__ Mre,
                                                    const float* __restrict__ Mim,
                                                    char* __restrict__ W2)
{
    if (blockIdx.x == 0 && threadIdx.x < 16) {
        const int s = threadIdx.x >> 2, i = (threadIdx.x >> 1) & 1, j = threadIdx.x & 1;
        g_mdre[threadIdx.x] =  Mre[s * 4 + j * 2 + i];
        g_mdim[threadIdx.x] = -Mim[s * 4 + j * 2 + i];
    }

    const int w = threadIdx.x >> 6, lane = threadIdx.x & 63;
    const int row = blockIdx.x * 4 + w;

    float ur[16], ui[16];
    const float* pr = P + (size_t)row * RANK + lane * 16;
    const float* pi = P + UELEMS + (size_t)row * RANK + lane * 16;
    #pragma unroll
    for (int q = 0; q < 4; ++q) {
        const float4 a = ((const float4*)pr)[q];
        const float4 b = ((const float4*)pi)[q];
        ur[q * 4 + 0] = a.x; ur[q * 4 + 1] = a.y; ur[q * 4 + 2] = a.z; ur[q * 4 + 3] = a.w;
        ui[q * 4 + 0] = b.x; ui[q * 4 + 1] = b.y; ui[q * 4 + 2] = b.z; ui[q * 4 + 3] = b.w;
    }
    float mx = 0.f;
    #pragma unroll
    for (int e = 0; e < 16; ++e)
        mx = fmaxf(mx, fmaxf(fabsf(ur[e]), fabsf(ui[e])));
    #pragma unroll
    for (int off = 1; off < 64; off <<= 1)
        mx = fmaxf(mx, __shfl_xor(mx, off));
    const float inv = mx > 0.f ? QSCALE / mx : 0.f;
    if (lane == 0) g_scale[row] = mx / QSCALE;

    int hr[16], lr[16], hi[16], li[16];
    #pragma unroll
    for (int e = 0; e < 16; ++e) {
        float q = ur[e] * inv;
        float hf = rintf(q * 0.0078125f);
        hr[e] = (int)hf; lr[e] = (int)rintf(q - 128.f * hf);
        q = ui[e] * inv;
        hf = rintf(q * 0.0078125f);
        hi[e] = (int)hf; li[e] = (int)rintf(q - 128.f * hf);
    }
    uint4 phr, plr, phi, pli;
    unsigned* dst[4] = {(unsigned*)&phr, (unsigned*)&plr, (unsigned*)&phi, (unsigned*)&pli};
    #pragma unroll
    for (int q = 0; q < 4; ++q) {
        unsigned a = 0, b = 0, c = 0, d = 0;
        #pragma unroll
        for (int k = 0; k < 4; ++k) {
            const int sh = k * 8;
            a |= (unsigned)(hr[q * 4 + k] & 255) << sh;
            b |= (unsigned)(lr[q * 4 + k] & 255) << sh;
            c |= (unsigned)(hi[q * 4 + k] & 255) << sh;
            d |= (unsigned)(li[q * 4 + k] & 255) << sh;
        }
        dst[0][q] = a; dst[1][q] = b; dst[2][q] = c; dst[3][q] = d;
    }

    // W2: k-major planes of 4 MB each; lane == k16, byte == k%16.
    const size_t b2 = ((size_t)lane * 4096 + row) * 16;
    *(uint4*)&W2[b2]            = phr;   // p0 = Ur high
    *(uint4*)&W2[b2 + 4194304]  = plr;   // p1 = Ur low
    *(uint4*)&W2[b2 + 8388608]  = phi;   // p2 = Ui high
    *(uint4*)&W2[b2 + 12582912] = pli;   // p3 = Ui low
}

// ---------------------------------------------------------------------------
// Fused Hermitian GEMM in i8. r17: ZERO-SYNC, LDS-FREE. Both A and B
// fragments are coalesced 16B/lane global loads from the k-major W2 (A and B
// come from the same matrix W, so one copy serves both):
//   frag(row r, k16 = kt*4+gq) = W2[p][k16][r][0..16)
// r11-r16 post-mortem: every variant kept a per-kt __syncthreads (to protect
// LDS staging), which re-exposed ~200-400 cy of load latency every kt on
// every wave — the entire 53->128 µs gap. With no LDS there is no barrier:
// the K-loop is pure dataflow, the compiler hoists kt+1 loads into kt's MFMA
// block, and waves drift into antiphase so vmem and MFMA pipes overlap.
// L2-BW floor: 2080 x 16kt x 64KB = 2.18 GB / 34.5 TB/s = 63 µs.
// ---------------------------------------------------------------------------
__global__ __launch_bounds__(256, 2) void gemm_rho_i8(const char* __restrict__ W2,
                                                      float2* __restrict__ rho)
{
    // XCD-chunk swizzle: 2080 = 8 * 260 exactly (bijective).
    const int g0 = blockIdx.x;
    const int g = (g0 & 7) * 260 + (g0 >> 3);

    int bi = (int)((sqrtf(8.f * (float)g + 1.f) - 1.f) * 0.5f);
    while (bi * (bi + 1) / 2 > g) --bi;
    while ((bi + 1) * (bi + 2) / 2 <= g) ++bi;
    const int bj = g - bi * (bi + 1) / 2;
    const int row0 = bi << 6, col0 = bj << 6;

    const int t = threadIdx.x;
    const int lane = t & 63, w = t >> 6;
    const int wr = w >> 1, wc = w & 1;          // 2x2 waves of 32x32

    const int m = lane & 15, gq = lane >> 4;

    // frag base addresses: W2[p][gq][idx][16B]; kt advances by 4*65536 B.
    const char* pa = W2 + ((size_t)gq * 4096 + row0 + wr * 32 + m) * 16;
    const char* pb = W2 + ((size_t)gq * 4096 + col0 + wc * 32 + m) * 16;

    i32x4 rehh[2][2], remx[2][2], iphh[2][2], ipmx[2][2], iqhh[2][2], iqmx[2][2];
    #pragma unroll
    for (int i = 0; i < 2; ++i)
        #pragma unroll
        for (int j = 0; j < 2; ++j) {
            rehh[i][j] = (i32x4){0, 0, 0, 0}; remx[i][j] = (i32x4){0, 0, 0, 0};
            iphh[i][j] = (i32x4){0, 0, 0, 0}; ipmx[i][j] = (i32x4){0, 0, 0, 0};
            iqhh[i][j] = (i32x4){0, 0, 0, 0}; iqmx[i][j] = (i32x4){0, 0, 0, 0};
        }

    #pragma unroll 4
    for (int kt = 0; kt < 16; ++kt) {
        const char* pA = pa + (size_t)kt * 262144;
        const char* pB = pb + (size_t)kt * 262144;

        i32x4 a1h[2], a1l[2], a2h[2], a2l[2];
        i32x4 b1h[2], b1l[2], b2h[2], b2l[2];
        #pragma unroll
        for (int i = 0; i < 2; ++i) {
            a1h[i] = *(const i32x4*)(pA + i * 256);
            a1l[i] = *(const i32x4*)(pA + 4194304  + i * 256);
            a2h[i] = *(const i32x4*)(pA + 8388608  + i * 256);
            a2l[i] = *(const i32x4*)(pA + 12582912 + i * 256);
        }
        #pragma unroll
        for (int j = 0; j < 2; ++j) {
            b1h[j] = *(const i32x4*)(pB + j * 256);
            b1l[j] = *(const i32x4*)(pB + 4194304  + j * 256);
            b2h[j] = *(const i32x4*)(pB + 8388608  + j * 256);
            b2l[j] = *(const i32x4*)(pB + 12582912 + j * 256);
        }

        #pragma unroll
        for (int j = 0; j < 2; ++j)
            #pragma unroll
            for (int i = 0; i < 2; ++i) {
                i32x4 r;
                r = rehh[i][j];
                r = MFMA_I8(a1h[i], b1h[j], r, 0, 0, 0);
                r = MFMA_I8(a2h[i], b2h[j], r, 0, 0, 0);
                rehh[i][j] = r;
                r = remx[i][j];
                r = MFMA_I8(a1h[i], b1l[j], r, 0, 0, 0);
                r = MFMA_I8(a1l[i], b1h[j], r, 0, 0, 0);
                r = MFMA_I8(a2h[i], b2l[j], r, 0, 0, 0);
                r = MFMA_I8(a2l[i], b2h[j], r, 0, 0, 0);
                remx[i][j] = r;
                r = MFMA_I8(a2h[i], b1h[j], iphh[i][j], 0, 0, 0);
                iphh[i][j] = r;
                r = ipmx[i][j];
                r = MFMA_I8(a2h[i], b1l[j], r, 0, 0, 0);
                r = MFMA_I8(a2l[i], b1h[j], r, 0, 0, 0);
                ipmx[i][j] = r;
                r = MFMA_I8(a1h[i], b2h[j], iqhh[i][j], 0, 0, 0);
                iqhh[i][j] = r;
                r = iqmx[i][j];
                r = MFMA_I8(a1h[i], b2l[j], r, 0, 0, 0);
                r = MFMA_I8(a1l[i], b2h[j], r, 0, 0, 0);
                iqmx[i][j] = r;
            }
    }

    #pragma unroll
    for (int j = 0; j < 2; ++j) {
        const int col = col0 + wc * 32 + j * 16 + m;
        const float sc = g_scale[col];
        const int c64 = col >> 6;
        #pragma unroll
        for (int i = 0; i < 2; ++i) {
            #pragma unroll
            for (int r = 0; r < 4; ++r) {
                const int row = row0 + wr * 32 + i * 16 + gq * 4 + r;
                const float s2 = g_scale[row] * sc;
                const float re = s2 * (16384.f * (float)rehh[i][j][r] + 128.f * (float)remx[i][j][r]);
                const float im = s2 * (16384.f * (float)(iphh[i][j][r] - iqhh[i][j][r])
                                      + 128.f * (float)(ipmx[i][j][r] - iqmx[i][j][r]));
                const int r64 = row >> 6;
                if (r64 > c64 || row >= col) rho[(size_t)row * D + col] = make_float2(re, im);
                if (r64 == c64 && row > col) rho[(size_t)col * D + row] = make_float2(re, -im);
            }
        }
    }
}

// ---------------------------------------------------------------------------
__global__ void trace_inv(const float2* __restrict__ rho)
{
    __shared__ float red[256];
    float s = 0.f;
    for (int d = threadIdx.x; d < D; d += 256)
        s += rho[(size_t)d * (D + 1)].x;
    red[threadIdx.x] = s;
    __syncthreads();
    for (int off = 128; off > 0; off >>= 1) {
        if (threadIdx.x < off) red[threadIdx.x] += red[threadIdx.x + off];
        __syncthreads();
    }
    if (threadIdx.x == 0) g_inv_tr[0] = 1.0f / red[0];
}

// ---------------------------------------------------------------------------
// 2-qubit staged contraction on a 4x4 register tile (verified r9).
// ---------------------------------------------------------------------------
static __device__ __forceinline__ void qmt2(float2* x,
                                            const float* __restrict__ Mre,
                                            const float* __restrict__ Mim)
{
    float2 y[16];
    #pragma unroll
    for (int sb = 0; sb < 4; ++sb)
        #pragma unroll
        for (int ja = 0; ja < 2; ++ja)
            #pragma unroll
            for (int ia = 0; ia < 2; ++ia) {
                float2 acc = make_float2(0.f, 0.f);
                #pragma unroll
                for (int ib = 0; ib < 2; ++ib)
                    #pragma unroll
                    for (int jb = 0; jb < 2; ++jb) {
                        const float mr = Mre[sb * 4 + ib * 2 + jb];
                        const float mi = Mim[sb * 4 + ib * 2 + jb];
                        const float2 v = x[(ja * 2 + jb) * 4 + ia * 2 + ib];
                        acc.x += mr * v.x - mi * v.y;
                        acc.y += mr * v.y + mi * v.x;
                    }
                y[sb * 4 + ja * 2 + ia] = acc;
            }
    #pragma unroll
    for (int sa = 0; sa < 4; ++sa)
        #pragma unroll
        for (int sb = 0; sb < 4; ++sb) {
            float2 acc = make_float2(0.f, 0.f);
            #pragma unroll
            for (int ia = 0; ia < 2; ++ia)
                #pragma unroll
                for (int ja = 0; ja < 2; ++ja) {
                    const float mr = Mre[sa * 4 + ia * 2 + ja];
                    const float mi = Mim[sa * 4 + ia * 2 + ja];
                    const float2 v = y[sb * 4 + ja * 2 + ia];
                    acc.x += mr * v.x - mi * v.y;
                    acc.y += mr * v.y + mi * v.x;
                }
            x[sa * 4 + sb] = acc;
        }
}

// ---------------------------------------------------------------------------
static __device__ __forceinline__ void pA_pipeline(float2* x, float2* X, const int t,
                                                   const float* __restrict__ mre,
                                                   const float* __restrict__ mim)
{
    qmt2(x, mre, mim);
    #pragma unroll
    for (int d = 0; d < 16; ++d) X[t * 17 + d] = x[d];
    __syncthreads();
    const int a2 = t >> 6, t2 = (t >> 4) & 3, d1 = t & 15;
    #pragma unroll
    for (int j2 = 0; j2 < 4; ++j2)
        #pragma unroll
        for (int i2 = 0; i2 < 4; ++i2)
            x[j2 * 4 + i2] = X[((a2 * 4 + j2) * 16 + t2 * 4 + i2) * 17 + d1];
    __syncthreads();
    qmt2(x, mre, mim);
    #pragma unroll
    for (int d = 0; d < 16; ++d) X[(a2 * 4 + t2) * 257 + d * 16 + d1] = x[d];
    __syncthreads();
    const int e2 = t >> 4, e1 = t & 15;
    #pragma unroll
    for (int j2 = 0; j2 < 4; ++j2)
        #pragma unroll
        for (int i2 = 0; i2 < 4; ++i2)
            x[j2 * 4 + i2] = X[(j2 * 4 + i2) * 257 + e2 * 16 + e1];
    qmt2(x, mre, mim);
}

// ---------------------------------------------------------------------------
// Fused pass A, Hermitian (r10): lower-triangle tiles, 2080 groups.
// ---------------------------------------------------------------------------
__global__ __launch_bounds__(256) void qmt_pAh(const float2* __restrict__ in,
                                               float2* __restrict__ out,
                                               const float* __restrict__ Mre,
                                               const float* __restrict__ Mim)
{
    __shared__ __align__(16) float2 X[256 * 17];   // 34816 B
    const int t = threadIdx.x;
    const int g = blockIdx.x;
    int rr = (int)((sqrtf(8.f * (float)g + 1.f) - 1.f) * 0.5f);
    while (rr * (rr + 1) / 2 > g) --rr;
    while ((rr + 1) * (rr + 2) / 2 <= g) ++rr;
    const int cc = g - rr * (rr + 1) / 2;          // cc <= rr

    const int a4 = t >> 4, t4 = t & 15;
    float2 x0[16], x[16];
    #pragma unroll
    for (int j2 = 0; j2 < 4; ++j2) {
        const float2* p = in + ((size_t)(rr * 64 + a4 * 4 + j2)) * 4096 + cc * 64 + t4 * 4;
        const float4 v0 = ((const float4*)p)[0];
        const float4 v1 = ((const float4*)p)[1];
        x0[j2 * 4 + 0] = make_float2(v0.x, v0.y);
        x0[j2 * 4 + 1] = make_float2(v0.z, v0.w);
        x0[j2 * 4 + 2] = make_float2(v1.x, v1.y);
        x0[j2 * 4 + 3] = make_float2(v1.z, v1.w);
    }

    #pragma unroll
    for (int q = 0; q < 16; ++q) x[q] = x0[q];
    pA_pipeline(x, X, t, Mre, Mim);
    const int e2 = t >> 4, e1 = t & 15;
    const size_t ob0 = (size_t)(rr * 64 + cc) * 4096 + e2 * 16 + e1;
    #pragma unroll
    for (int d = 0; d < 16; ++d) out[ob0 + (size_t)d * 256] = x[d];

    if (rr != cc) {
        __syncthreads();
        #pragma unroll
        for (int q = 0; q < 16; ++q) x[q] = x0[q];
        pA_pipeline(x, X, t, g_mdre, g_mdim);
        const size_t ob1 = (size_t)(cc * 64 + rr) * 4096 + e2 * 16 + e1;
        #pragma unroll
        for (int d = 0; d < 16; ++d)
            out[ob1 + (size_t)d * 256] = make_float2(x[d].x, -x[d].y);
    }
}

// ---------------------------------------------------------------------------
// r12 half-tile 3-qubit contraction (verified round-2/4 WIN). Each thread
// owns the ja = h half; stages c,b local; stage a via __shfl_xor(.,32).
// ---------------------------------------------------------------------------
static __device__ __forceinline__ void qmt_stage_cb_half(float2* x,
                                                         const float* __restrict__ Mre,
                                                         const float* __restrict__ Mim)
{
    #pragma unroll
    for (int jb = 0; jb < 2; ++jb) {
        float2 y[16];
        #pragma unroll
        for (int sc = 0; sc < 4; ++sc)
            #pragma unroll
            for (int ii = 0; ii < 4; ++ii) {
                float2 acc = make_float2(0.f, 0.f);
                #pragma unroll
                for (int ic = 0; ic < 2; ++ic)
                    #pragma unroll
                    for (int jc = 0; jc < 2; ++jc) {
                        const float mr = Mre[sc * 4 + ic * 2 + jc];
                        const float mi = Mim[sc * 4 + ic * 2 + jc];
                        const float2 v = x[jb * 16 + jc * 8 + ii * 2 + ic];
                        acc.x += mr * v.x - mi * v.y;
                        acc.y += mr * v.y + mi * v.x;
                    }
                y[sc * 4 + ii] = acc;
            }
        #pragma unroll
        for (int q = 0; q < 16; ++q) x[jb * 16 + q] = y[q];
    }
    #pragma unroll
    for (int sc = 0; sc < 4; ++sc) {
        float2 z[8];
        #pragma unroll
        for (int sb = 0; sb < 4; ++sb)
            #pragma unroll
            for (int ia = 0; ia < 2; ++ia) {
                float2 acc = make_float2(0.f, 0.f);
                #pragma unroll
                for (int ib = 0; ib < 2; ++ib)
                    #pragma unroll
                    for (int jb = 0; jb < 2; ++jb) {
                        const float mr = Mre[sb * 4 + ib * 2 + jb];
                        const float mi = Mim[sb * 4 + ib * 2 + jb];
                        const float2 v = x[jb * 16 + sc * 4 + ia * 2 + ib];
                        acc.x += mr * v.x - mi * v.y;
                        acc.y += mr * v.y + mi * v.x;
                    }
                z[sb * 2 + ia] = acc;
            }
        #pragma unroll
        for (int sb = 0; sb < 4; ++sb)
            #pragma unroll
            for (int ia = 0; ia < 2; ++ia)
                x[(sb >> 1) * 16 + sc * 4 + ia * 2 + (sb & 1)] = z[sb * 2 + ia];
    }
}

#define STAGE_A_COEFFS                                                        \
    float Are[2][2], Aim[2][2], Bre[2][2], Bim[2][2];                         \
    _Pragma("unroll")                                                         \
    for (int sal = 0; sal < 2; ++sal)                                         \
        _Pragma("unroll")                                                     \
        for (int ia = 0; ia < 2; ++ia) {                                      \
            const int sa = 2 * h + sal;                                       \
            Are[sal][ia] = Mre[sa * 4 + ia * 2 + h];                          \
            Aim[sal][ia] = Mim[sa * 4 + ia * 2 + h];                          \
            Bre[sal][ia] = Mre[sa * 4 + ia * 2 + (1 - h)];                    \
            Bim[sal][ia] = Mim[sa * 4 + ia * 2 + (1 - h)];                    \
        }

// ---------------------------------------------------------------------------
// Pass B (= p3), r12: in [rr(64), cc(64), S(4096)]; out [r3,c3, s3(64), S].
// 2048 blocks x 256 threads; lane pair (l, l^32) shares one (r3,c3,s) tile.
// ---------------------------------------------------------------------------
__global__ __launch_bounds__(256) void qmt_p3(const float2* __restrict__ in,
                                              float2* __restrict__ out,
                                              const float* __restrict__ Mre,
                                              const float* __restrict__ Mim)
{
    const int t = threadIdx.x;
    const int h = (t >> 5) & 1;
    const int idx = blockIdx.x * 4 + (t >> 6);     // [0, 8192)
    const int rc = idx >> 7;                       // [0, 64)
    const int r3 = rc >> 3, c3 = rc & 7;
    const int s = (idx & 127) * 32 + (t & 31);     // [0, 4096)

    float2 x[32];
    #pragma unroll
    for (int jb = 0; jb < 2; ++jb)
        #pragma unroll
        for (int jc = 0; jc < 2; ++jc) {
            const int j3 = 4 * h + 2 * jb + jc;
            #pragma unroll
            for (int i3 = 0; i3 < 8; ++i3)
                x[jb * 16 + jc * 8 + i3] =
                    in[(size_t)((r3 * 8 + j3) * 64 + c3 * 8 + i3) * 4096 + s];
        }

    qmt_stage_cb_half(x, Mre, Mim);

    STAGE_A_COEFFS
    const size_t ob = ((size_t)(r3 * 8 + c3) * 64) * 4096 + s;
    #pragma unroll
    for (int sbH = 0; sbH < 2; ++sbH)
        #pragma unroll
        for (int sc = 0; sc < 4; ++sc)
            #pragma unroll
            for (int sbL = 0; sbL < 2; ++sbL) {
                const int q = sbH * 16 + sc * 4 + sbL;
                const float2 o0 = x[q], o1 = x[q + 2];
                float2 r0, r1;
                r0.x = __shfl_xor(o0.x, 32); r0.y = __shfl_xor(o0.y, 32);
                r1.x = __shfl_xor(o1.x, 32); r1.y = __shfl_xor(o1.y, 32);
                const int sb = sbH * 2 + sbL;
                #pragma unroll
                for (int sal = 0; sal < 2; ++sal) {
                    const float re = Are[sal][0] * o0.x - Aim[sal][0] * o0.y
                                   + Are[sal][1] * o1.x - Aim[sal][1] * o1.y
                                   + Bre[sal][0] * r0.x - Bim[sal][0] * r0.y
                                   + Bre[sal][1] * r1.x - Bim[sal][1] * r1.y;
                    const float im = Are[sal][0] * o0.y + Aim[sal][0] * o0.x
                                   + Are[sal][1] * o1.y + Aim[sal][1] * o1.x
                                   + Bre[sal][0] * r0.y + Bim[sal][0] * r0.x
                                   + Bre[sal][1] * r1.y + Bim[sal][1] * r1.x;
                    const int s3 = (2 * h + sal) * 16 + sb * 4 + sc;
                    out[ob + (size_t)s3 * 4096] = make_float2(re, im);
                }
            }
}

// ---------------------------------------------------------------------------
// Pass C (= p4, MSB triplet), r12: real-only out [s_hi, s3(64), s_lo(32)].
// 2048 blocks x 256 threads.
// ---------------------------------------------------------------------------
__global__ __launch_bounds__(256) void qmt_p4(const float2* __restrict__ in,
                                              float* __restrict__ out,
                                              const float* __restrict__ Mre,
                                              const float* __restrict__ Mim)
{
    const int t = threadIdx.x;
    const int h = (t >> 5) & 1;
    const int s = (blockIdx.x * 4 + (t >> 6)) * 32 + (t & 31);   // [0, 2^18)

    float2 x[32];
    #pragma unroll
    for (int jb = 0; jb < 2; ++jb)
        #pragma unroll
        for (int jc = 0; jc < 2; ++jc) {
            const int j3 = 4 * h + 2 * jb + jc;
            #pragma unroll
            for (int i3 = 0; i3 < 8; ++i3)
                x[jb * 16 + jc * 8 + i3] = in[(size_t)(j3 * 8 + i3) * 262144 + s];
        }

    qmt_stage_cb_half(x, Mre, Mim);

    STAGE_A_COEFFS
    const size_t ob = (size_t)(s >> 5) * 2048 + (s & 31);
    #pragma unroll
    for (int sbH = 0; sbH < 2; ++sbH)
        #pragma unroll
        for (int sc = 0; sc < 4; ++sc)
            #pragma unroll
            for (int sbL = 0; sbL < 2; ++sbL) {
                const int q = sbH * 16 + sc * 4 + sbL;
                const float2 o0 = x[q], o1 = x[q + 2];
                float2 r0, r1;
                r0.x = __shfl_xor(o0.x, 32); r0.y = __shfl_xor(o0.y, 32);
                r1.x = __shfl_xor(o1.x, 32); r1.y = __shfl_xor(o1.y, 32);
                const int sb = sbH * 2 + sbL;
                #pragma unroll
                for (int sal = 0; sal < 2; ++sal) {
                    const float re = Are[sal][0] * o0.x - Aim[sal][0] * o0.y
                                   + Are[sal][1] * o1.x - Aim[sal][1] * o1.y
                                   + Bre[sal][0] * r0.x - Bim[sal][0] * r0.y
                                   + Bre[sal][1] * r1.x - Bim[sal][1] * r1.y;
                    const int s3 = (2 * h + sal) * 16 + sb * 4 + sc;
                    out[ob + (size_t)s3 * 32] = re;
                }
            }
}

// ---------------------------------------------------------------------------
__global__ void gather_idx(const float* __restrict__ P, const int* __restrict__ idxs,
                           float* __restrict__ out, const int n)
{
    const int i = blockIdx.x * 256 + threadIdx.x;
    if (i < n) {
        const int idx = idxs[i];
        const int s = idx & 262143;
        const size_t pos = (size_t)(s >> 5) * 2048 + (size_t)(idx >> 18) * 32 + (s & 31);
        out[i] = P[pos] * g_inv_tr[0];
    }
}

// ---------------------------------------------------------------------------
extern "C" void kernel_launch(void* const* d_in, const int* in_sizes, int n_in,
                              void* d_out, int out_size, void* d_ws, size_t ws_size,
                              hipStream_t stream)
{
    const float* params = (const float*)d_in[0];  // (2, D, RANK) fp32
    const float* Mre    = (const float*)d_in[1];
    const float* Mim    = (const float*)d_in[2];
    const int*   idxs   = (const int*)d_in[3];
    float*       out    = (float*)d_out;

    float* ws = (float*)d_ws;
    float2* A  = (float2*)ws;                 // 134 MB plane
    float2* Bp = (float2*)(ws + 2 * NTOT);    // 134 MB plane
    char* W2 = (char*)Bp;                     // 16 MB k-major i8 copy

    convert_w_i8<<<1024, 256, 0, stream>>>(params, Mre, Mim, W2);
    gemm_rho_i8<<<2080, 256, 0, stream>>>(W2, A);
    trace_inv<<<1, 256, 0, stream>>>(A);

    qmt_pAh<<<2080, 256, 0, stream>>>(A, Bp, Mre, Mim);  // 6 LSB qubits, triangle
    qmt_p3<<<2048, 256, 0, stream>>>(Bp, A, Mre, Mim);   // 3 qubits, half-split
    qmt_p4<<<2048, 256, 0, stream>>>(A, (float*)Bp, Mre, Mim);  // 3 qubits, real out

    gather_idx<<<(out_size + 255) / 256, 256, 0, stream>>>((float*)Bp, idxs, out, out_size);
}

// Round 8
// 395.703 us; speedup vs baseline: 1.0803x; 1.0803x over previous
//
#include <hip/hip_runtime.h>

#define D 4096
#define RANK 1024
#define UELEMS 4194304ULL   // D*RANK
#define NTOT 16777216ULL    // 4^12 = D*D
#define QSCALE 16000.0f

typedef __attribute__((ext_vector_type(4))) int i32x4;

__device__ float g_inv_tr[1];
__device__ float g_scale[D];
__device__ float g_mdre[16];   // M-dagger tables: M†[s][i][j] = conj(M[s][j][i])
__device__ float g_mdim[16];

static __device__ __forceinline__ void load_lds16(const void* g, void* l) {
    __builtin_amdgcn_global_load_lds(
        (const __attribute__((address_space(1))) unsigned int*)g,
        (__attribute__((address_space(3))) unsigned int*)l, 16, 0, 0);
}

#define MFMA_I8 __builtin_amdgcn_mfma_i32_16x16x64_i8

// ---------------------------------------------------------------------------
// i8 split quantization of W = [Ur | Ui] with per-row scale (verified r6).
// ---------------------------------------------------------------------------
__global__ __launch_bounds__(256) void convert_w_i8(const float* __restrict__ P,
                                                    const float* __restrict__ Mre,
                                                    const float* __restrict__ Mim,
                                                    char* __restrict__ Wh,
                                                    char* __restrict__ Wl)
{
    if (blockIdx.x == 0 && threadIdx.x < 16) {
        const int s = threadIdx.x >> 2, i = (threadIdx.x >> 1) & 1, j = threadIdx.x & 1;
        g_mdre[threadIdx.x] =  Mre[s * 4 + j * 2 + i];
        g_mdim[threadIdx.x] = -Mim[s * 4 + j * 2 + i];
    }

    const int w = threadIdx.x >> 6, lane = threadIdx.x & 63;
    const int row = blockIdx.x * 4 + w;

    float ur[16], ui[16];
    const float* pr = P + (size_t)row * RANK + lane * 16;
    const float* pi = P + UELEMS + (size_t)row * RANK + lane * 16;
    #pragma unroll
    for (int q = 0; q < 4; ++q) {
        const float4 a = ((const float4*)pr)[q];
        const float4 b = ((const float4*)pi)[q];
        ur[q * 4 + 0] = a.x; ur[q * 4 + 1] = a.y; ur[q * 4 + 2] = a.z; ur[q * 4 + 3] = a.w;
        ui[q * 4 + 0] = b.x; ui[q * 4 + 1] = b.y; ui[q * 4 + 2] = b.z; ui[q * 4 + 3] = b.w;
    }
    float mx = 0.f;
    #pragma unroll
    for (int e = 0; e < 16; ++e)
        mx = fmaxf(mx, fmaxf(fabsf(ur[e]), fabsf(ui[e])));
    #pragma unroll
    for (int off = 1; off < 64; off <<= 1)
        mx = fmaxf(mx, __shfl_xor(mx, off));
    const float inv = mx > 0.f ? QSCALE / mx : 0.f;
    if (lane == 0) g_scale[row] = mx / QSCALE;

    int hr[16], lr[16], hi[16], li[16];
    #pragma unroll
    for (int e = 0; e < 16; ++e) {
        float q = ur[e] * inv;
        float hf = rintf(q * 0.0078125f);
        hr[e] = (int)hf; lr[e] = (int)rintf(q - 128.f * hf);
        q = ui[e] * inv;
        hf = rintf(q * 0.0078125f);
        hi[e] = (int)hf; li[e] = (int)rintf(q - 128.f * hf);
    }
    uint4 phr, plr, phi, pli;
    unsigned* dst[4] = {(unsigned*)&phr, (unsigned*)&plr, (unsigned*)&phi, (unsigned*)&pli};
    #pragma unroll
    for (int q = 0; q < 4; ++q) {
        unsigned a = 0, b = 0, c = 0, d = 0;
        #pragma unroll
        for (int k = 0; k < 4; ++k) {
            const int sh = k * 8;
            a |= (unsigned)(hr[q * 4 + k] & 255) << sh;
            b |= (unsigned)(lr[q * 4 + k] & 255) << sh;
            c |= (unsigned)(hi[q * 4 + k] & 255) << sh;
            d |= (unsigned)(li[q * 4 + k] & 255) << sh;
        }
        dst[0][q] = a; dst[1][q] = b; dst[2][q] = c; dst[3][q] = d;
    }
    const size_t b1 = (size_t)row * 2048 + lane * 16;
    *(uint4*)&Wh[b1] = phr;          *(uint4*)&Wl[b1] = plr;
    *(uint4*)&Wh[b1 + 1024] = phi;   *(uint4*)&Wl[b1 + 1024] = pli;
}

// ---------------------------------------------------------------------------
// Fused Hermitian GEMM in i8. r18 = r14 (verified best, 123 µs) + bijective
// XCD-chunk swizzle (the only untested isolated delta from r16/r17).
// 64x64 tile, 256 threads (2x2 waves of 32x32), double-buffered LDS = 64 KB
// -> 2 blocks/CU. One __syncthreads per kt (publishes staging + buffer swap).
// Ledger: LDS-both+sync 123 / B-global 128 / no-sync 137 / reg-dbuf 141 /
// 128x64 phases 128 — r14 is the verified optimum of this family.
// im = P - Q (exact int) in epilogue.
// ---------------------------------------------------------------------------
__global__ __launch_bounds__(256, 2) void gemm_rho_i8(const char* __restrict__ Wh,
                                                      const char* __restrict__ Wl,
                                                      float2* __restrict__ rho)
{
    __shared__ __align__(16) char sA[2][4][64 * 64];   // 32768 B
    __shared__ __align__(16) char sB[2][4][64 * 64];   // 32768 B

    // XCD-chunk swizzle: 2080 = 8 * 260 exactly (bijective); 260 consecutive
    // triangle tiles per XCD share A-panels -> per-XCD L2 reuse.
    const int g0 = blockIdx.x;
    const int g = (g0 & 7) * 260 + (g0 >> 3);

    int bi = (int)((sqrtf(8.f * (float)g + 1.f) - 1.f) * 0.5f);
    while (bi * (bi + 1) / 2 > g) --bi;
    while ((bi + 1) * (bi + 2) / 2 <= g) ++bi;
    const int bj = g - bi * (bi + 1) / 2;
    const int row0 = bi << 6, col0 = bj << 6;

    const int t = threadIdx.x;
    const int lane = t & 63, w = t >> 6;
    const int wr = w >> 1, wc = w & 1;          // 2x2 waves of 32x32

    // staging: 64 rows x 64 B per plane; thread t covers row t>>2, slot t&3
    const int ra = t >> 2;
    const int kca = (t & 3) ^ ((ra >> 1) & 3);  // xor-swizzled k-slot
    const size_t aoff = (size_t)(row0 + ra) * 2048 + kca * 16;
    const size_t boff = (size_t)(col0 + ra) * 2048 + kca * 16;
    const int ldso = t * 16;                    // linear LDS dest within plane

    const int m = lane & 15, gq = lane >> 4;
    const int fko = (gq ^ ((m >> 1) & 3)) * 16;

    i32x4 rehh[2][2], remx[2][2], iphh[2][2], ipmx[2][2], iqhh[2][2], iqmx[2][2];
    #pragma unroll
    for (int i = 0; i < 2; ++i)
        #pragma unroll
        for (int j = 0; j < 2; ++j) {
            rehh[i][j] = (i32x4){0, 0, 0, 0}; remx[i][j] = (i32x4){0, 0, 0, 0};
            iphh[i][j] = (i32x4){0, 0, 0, 0}; ipmx[i][j] = (i32x4){0, 0, 0, 0};
            iqhh[i][j] = (i32x4){0, 0, 0, 0}; iqmx[i][j] = (i32x4){0, 0, 0, 0};
        }

    char* const sA0 = &sA[0][0][0];
    char* const sB0 = &sB[0][0][0];

    // prologue: stage kt=0 into buffer 0
    load_lds16(Wh + aoff,        sA0 + ldso);
    load_lds16(Wl + aoff,        sA0 + 4096  + ldso);
    load_lds16(Wh + aoff + 1024, sA0 + 8192  + ldso);
    load_lds16(Wl + aoff + 1024, sA0 + 12288 + ldso);
    load_lds16(Wh + boff,        sB0 + ldso);
    load_lds16(Wl + boff,        sB0 + 4096  + ldso);
    load_lds16(Wh + boff + 1024, sB0 + 8192  + ldso);
    load_lds16(Wl + boff + 1024, sB0 + 12288 + ldso);
    __syncthreads();

#define DO_MFMA_J(j)                                                          \
    _Pragma("unroll")                                                         \
    for (int i = 0; i < 2; ++i) {                                             \
        i32x4 r;                                                              \
        r = rehh[i][j];                                                       \
        r = MFMA_I8(fa1h[i], b1h[j], r, 0, 0, 0);                             \
        r = MFMA_I8(fa2h[i], b2h[j], r, 0, 0, 0);                             \
        rehh[i][j] = r;                                                       \
        r = remx[i][j];                                                       \
        r = MFMA_I8(fa1h[i], b1l[j], r, 0, 0, 0);                             \
        r = MFMA_I8(fa1l[i], b1h[j], r, 0, 0, 0);                             \
        r = MFMA_I8(fa2h[i], b2l[j], r, 0, 0, 0);                             \
        r = MFMA_I8(fa2l[i], b2h[j], r, 0, 0, 0);                             \
        remx[i][j] = r;                                                       \
        r = MFMA_I8(fa2h[i], b1h[j], iphh[i][j], 0, 0, 0); iphh[i][j] = r;    \
        r = ipmx[i][j];                                                       \
        r = MFMA_I8(fa2h[i], b1l[j], r, 0, 0, 0);                             \
        r = MFMA_I8(fa2l[i], b1h[j], r, 0, 0, 0);                             \
        ipmx[i][j] = r;                                                       \
        r = MFMA_I8(fa1h[i], b2h[j], iqhh[i][j], 0, 0, 0); iqhh[i][j] = r;    \
        r = iqmx[i][j];                                                       \
        r = MFMA_I8(fa1h[i], b2l[j], r, 0, 0, 0);                             \
        r = MFMA_I8(fa1l[i], b2h[j], r, 0, 0, 0);                             \
        iqmx[i][j] = r;                                                       \
    }

    #pragma unroll 2
    for (int kt = 0; kt < 16; ++kt) {
        const int cur = kt & 1;
        const char* sAc = sA0 + cur * 16384;
        const char* sBc = sB0 + cur * 16384;
        char* sAn = sA0 + (cur ^ 1) * 16384;
        char* sBn = sB0 + (cur ^ 1) * 16384;
        const size_t ko = (size_t)(kt + 1) * 64;

        // stage kt+1 first: readers of the target buffer finished at the
        // previous __syncthreads; the end-of-kt drain sits behind compute.
        if (kt < 15) {
            load_lds16(Wh + aoff + ko,        sAn + ldso);
            load_lds16(Wl + aoff + ko,        sAn + 4096  + ldso);
            load_lds16(Wh + aoff + ko + 1024, sAn + 8192  + ldso);
            load_lds16(Wl + aoff + ko + 1024, sAn + 12288 + ldso);
            load_lds16(Wh + boff + ko,        sBn + ldso);
            load_lds16(Wl + boff + ko,        sBn + 4096  + ldso);
            load_lds16(Wh + boff + ko + 1024, sBn + 8192  + ldso);
            load_lds16(Wl + boff + ko + 1024, sBn + 12288 + ldso);
        }

        i32x4 fa1h[2], fa1l[2], fa2h[2], fa2l[2];
        i32x4 b1h[2], b1l[2], b2h[2], b2l[2];
        #pragma unroll
        for (int i = 0; i < 2; ++i) {
            const int off = (wr * 32 + i * 16 + m) * 64 + fko;
            fa1h[i] = *(const i32x4*)(sAc + off);
            fa1l[i] = *(const i32x4*)(sAc + 4096  + off);
            fa2h[i] = *(const i32x4*)(sAc + 8192  + off);
            fa2l[i] = *(const i32x4*)(sAc + 12288 + off);
        }
        #pragma unroll
        for (int j = 0; j < 2; ++j) {
            const int off = (wc * 32 + j * 16 + m) * 64 + fko;
            b1h[j] = *(const i32x4*)(sBc + off);
            b1l[j] = *(const i32x4*)(sBc + 4096  + off);
            b2h[j] = *(const i32x4*)(sBc + 8192  + off);
            b2l[j] = *(const i32x4*)(sBc + 12288 + off);
        }

        __builtin_amdgcn_s_setprio(1);
        DO_MFMA_J(0)
        DO_MFMA_J(1)
        __builtin_amdgcn_s_setprio(0);

        // publishes kt+1 staging (vmcnt drain) + protects buffer swap
        __syncthreads();
    }
#undef DO_MFMA_J

    #pragma unroll
    for (int j = 0; j < 2; ++j) {
        const int col = col0 + wc * 32 + j * 16 + m;
        const float sc = g_scale[col];
        const int c64 = col >> 6;
        #pragma unroll
        for (int i = 0; i < 2; ++i) {
            #pragma unroll
            for (int r = 0; r < 4; ++r) {
                const int row = row0 + wr * 32 + i * 16 + gq * 4 + r;
                const float s2 = g_scale[row] * sc;
                const float re = s2 * (16384.f * (float)rehh[i][j][r] + 128.f * (float)remx[i][j][r]);
                const float im = s2 * (16384.f * (float)(iphh[i][j][r] - iqhh[i][j][r])
                                      + 128.f * (float)(ipmx[i][j][r] - iqmx[i][j][r]));
                const int r64 = row >> 6;
                if (r64 > c64 || row >= col) rho[(size_t)row * D + col] = make_float2(re, im);
                if (r64 == c64 && row > col) rho[(size_t)col * D + row] = make_float2(re, -im);
            }
        }
    }
}

// ---------------------------------------------------------------------------
__global__ void trace_inv(const float2* __restrict__ rho)
{
    __shared__ float red[256];
    float s = 0.f;
    for (int d = threadIdx.x; d < D; d += 256)
        s += rho[(size_t)d * (D + 1)].x;
    red[threadIdx.x] = s;
    __syncthreads();
    for (int off = 128; off > 0; off >>= 1) {
        if (threadIdx.x < off) red[threadIdx.x] += red[threadIdx.x + off];
        __syncthreads();
    }
    if (threadIdx.x == 0) g_inv_tr[0] = 1.0f / red[0];
}

// ---------------------------------------------------------------------------
// 2-qubit staged contraction on a 4x4 register tile (verified r9).
// ---------------------------------------------------------------------------
static __device__ __forceinline__ void qmt2(float2* x,
                                            const float* __restrict__ Mre,
                                            const float* __restrict__ Mim)
{
    float2 y[16];
    #pragma unroll
    for (int sb = 0; sb < 4; ++sb)
        #pragma unroll
        for (int ja = 0; ja < 2; ++ja)
            #pragma unroll
            for (int ia = 0; ia < 2; ++ia) {
                float2 acc = make_float2(0.f, 0.f);
                #pragma unroll
                for (int ib = 0; ib < 2; ++ib)
                    #pragma unroll
                    for (int jb = 0; jb < 2; ++jb) {
                        const float mr = Mre[sb * 4 + ib * 2 + jb];
                        const float mi = Mim[sb * 4 + ib * 2 + jb];
                        const float2 v = x[(ja * 2 + jb) * 4 + ia * 2 + ib];
                        acc.x += mr * v.x - mi * v.y;
                        acc.y += mr * v.y + mi * v.x;
                    }
                y[sb * 4 + ja * 2 + ia] = acc;
            }
    #pragma unroll
    for (int sa = 0; sa < 4; ++sa)
        #pragma unroll
        for (int sb = 0; sb < 4; ++sb) {
            float2 acc = make_float2(0.f, 0.f);
            #pragma unroll
            for (int ia = 0; ia < 2; ++ia)
                #pragma unroll
                for (int ja = 0; ja < 2; ++ja) {
                    const float mr = Mre[sa * 4 + ia * 2 + ja];
                    const float mi = Mim[sa * 4 + ia * 2 + ja];
                    const float2 v = y[sb * 4 + ja * 2 + ia];
                    acc.x += mr * v.x - mi * v.y;
                    acc.y += mr * v.y + mi * v.x;
                }
            x[sa * 4 + sb] = acc;
        }
}

// ---------------------------------------------------------------------------
static __device__ __forceinline__ void pA_pipeline(float2* x, float2* X, const int t,
                                                   const float* __restrict__ mre,
                                                   const float* __restrict__ mim)
{
    qmt2(x, mre, mim);
    #pragma unroll
    for (int d = 0; d < 16; ++d) X[t * 17 + d] = x[d];
    __syncthreads();
    const int a2 = t >> 6, t2 = (t >> 4) & 3, d1 = t & 15;
    #pragma unroll
    for (int j2 = 0; j2 < 4; ++j2)
        #pragma unroll
        for (int i2 = 0; i2 < 4; ++i2)
            x[j2 * 4 + i2] = X[((a2 * 4 + j2) * 16 + t2 * 4 + i2) * 17 + d1];
    __syncthreads();
    qmt2(x, mre, mim);
    #pragma unroll
    for (int d = 0; d < 16; ++d) X[(a2 * 4 + t2) * 257 + d * 16 + d1] = x[d];
    __syncthreads();
    const int e2 = t >> 4, e1 = t & 15;
    #pragma unroll
    for (int j2 = 0; j2 < 4; ++j2)
        #pragma unroll
        for (int i2 = 0; i2 < 4; ++i2)
            x[j2 * 4 + i2] = X[(j2 * 4 + i2) * 257 + e2 * 16 + e1];
    qmt2(x, mre, mim);
}

// ---------------------------------------------------------------------------
// Fused pass A, Hermitian (r10): lower-triangle tiles, 2080 groups.
// ---------------------------------------------------------------------------
__global__ __launch_bounds__(256) void qmt_pAh(const float2* __restrict__ in,
                                               float2* __restrict__ out,
                                               const float* __restrict__ Mre,
                                               const float* __restrict__ Mim)
{
    __shared__ __align__(16) float2 X[256 * 17];   // 34816 B
    const int t = threadIdx.x;
    const int g = blockIdx.x;
    int rr = (int)((sqrtf(8.f * (float)g + 1.f) - 1.f) * 0.5f);
    while (rr * (rr + 1) / 2 > g) --rr;
    while ((rr + 1) * (rr + 2) / 2 <= g) ++rr;
    const int cc = g - rr * (rr + 1) / 2;          // cc <= rr

    const int a4 = t >> 4, t4 = t & 15;
    float2 x0[16], x[16];
    #pragma unroll
    for (int j2 = 0; j2 < 4; ++j2) {
        const float2* p = in + ((size_t)(rr * 64 + a4 * 4 + j2)) * 4096 + cc * 64 + t4 * 4;
        const float4 v0 = ((const float4*)p)[0];
        const float4 v1 = ((const float4*)p)[1];
        x0[j2 * 4 + 0] = make_float2(v0.x, v0.y);
        x0[j2 * 4 + 1] = make_float2(v0.z, v0.w);
        x0[j2 * 4 + 2] = make_float2(v1.x, v1.y);
        x0[j2 * 4 + 3] = make_float2(v1.z, v1.w);
    }

    #pragma unroll
    for (int q = 0; q < 16; ++q) x[q] = x0[q];
    pA_pipeline(x, X, t, Mre, Mim);
    const int e2 = t >> 4, e1 = t & 15;
    const size_t ob0 = (size_t)(rr * 64 + cc) * 4096 + e2 * 16 + e1;
    #pragma unroll
    for (int d = 0; d < 16; ++d) out[ob0 + (size_t)d * 256] = x[d];

    if (rr != cc) {
        __syncthreads();
        #pragma unroll
        for (int q = 0; q < 16; ++q) x[q] = x0[q];
        pA_pipeline(x, X, t, g_mdre, g_mdim);
        const size_t ob1 = (size_t)(cc * 64 + rr) * 4096 + e2 * 16 + e1;
        #pragma unroll
        for (int d = 0; d < 16; ++d)
            out[ob1 + (size_t)d * 256] = make_float2(x[d].x, -x[d].y);
    }
}

// ---------------------------------------------------------------------------
// r12 half-tile 3-qubit contraction (verified round-2/4 WIN). Each thread
// owns the ja = h half; stages c,b local; stage a via __shfl_xor(.,32).
// ---------------------------------------------------------------------------
static __device__ __forceinline__ void qmt_stage_cb_half(float2* x,
                                                         const float* __restrict__ Mre,
                                                         const float* __restrict__ Mim)
{
    #pragma unroll
    for (int jb = 0; jb < 2; ++jb) {
        float2 y[16];
        #pragma unroll
        for (int sc = 0; sc < 4; ++sc)
            #pragma unroll
            for (int ii = 0; ii < 4; ++ii) {
                float2 acc = make_float2(0.f, 0.f);
                #pragma unroll
                for (int ic = 0; ic < 2; ++ic)
                    #pragma unroll
                    for (int jc = 0; jc < 2; ++jc) {
                        const float mr = Mre[sc * 4 + ic * 2 + jc];
                        const float mi = Mim[sc * 4 + ic * 2 + jc];
                        const float2 v = x[jb * 16 + jc * 8 + ii * 2 + ic];
                        acc.x += mr * v.x - mi * v.y;
                        acc.y += mr * v.y + mi * v.x;
                    }
                y[sc * 4 + ii] = acc;
            }
        #pragma unroll
        for (int q = 0; q < 16; ++q) x[jb * 16 + q] = y[q];
    }
    #pragma unroll
    for (int sc = 0; sc < 4; ++sc) {
        float2 z[8];
        #pragma unroll
        for (int sb = 0; sb < 4; ++sb)
            #pragma unroll
            for (int ia = 0; ia < 2; ++ia) {
                float2 acc = make_float2(0.f, 0.f);
                #pragma unroll
                for (int ib = 0; ib < 2; ++ib)
                    #pragma unroll
                    for (int jb = 0; jb < 2; ++jb) {
                        const float mr = Mre[sb * 4 + ib * 2 + jb];
                        const float mi = Mim[sb * 4 + ib * 2 + jb];
                        const float2 v = x[jb * 16 + sc * 4 + ia * 2 + ib];
                        acc.x += mr * v.x - mi * v.y;
                        acc.y += mr * v.y + mi * v.x;
                    }
                z[sb * 2 + ia] = acc;
            }
        #pragma unroll
        for (int sb = 0; sb < 4; ++sb)
            #pragma unroll
            for (int ia = 0; ia < 2; ++ia)
                x[(sb >> 1) * 16 + sc * 4 + ia * 2 + (sb & 1)] = z[sb * 2 + ia];
    }
}

#define STAGE_A_COEFFS                                                        \
    float Are[2][2], Aim[2][2], Bre[2][2], Bim[2][2];                         \
    _Pragma("unroll")                                                         \
    for (int sal = 0; sal < 2; ++sal)                                         \
        _Pragma("unroll")                                                     \
        for (int ia = 0; ia < 2; ++ia) {                                      \
            const int sa = 2 * h + sal;                                       \
            Are[sal][ia] = Mre[sa * 4 + ia * 2 + h];                          \
            Aim[sal][ia] = Mim[sa * 4 + ia * 2 + h];                          \
            Bre[sal][ia] = Mre[sa * 4 + ia * 2 + (1 - h)];                    \
            Bim[sal][ia] = Mim[sa * 4 + ia * 2 + (1 - h)];                    \
        }

// ---------------------------------------------------------------------------
// Pass B (= p3), r12: in [rr(64), cc(64), S(4096)]; out [r3,c3, s3(64), S].
// 2048 blocks x 256 threads; lane pair (l, l^32) shares one (r3,c3,s) tile.
// ---------------------------------------------------------------------------
__global__ __launch_bounds__(256) void qmt_p3(const float2* __restrict__ in,
                                              float2* __restrict__ out,
                                              const float* __restrict__ Mre,
                                              const float* __restrict__ Mim)
{
    const int t = threadIdx.x;
    const int h = (t >> 5) & 1;
    const int idx = blockIdx.x * 4 + (t >> 6);     // [0, 8192)
    const int rc = idx >> 7;                       // [0, 64)
    const int r3 = rc >> 3, c3 = rc & 7;
    const int s = (idx & 127) * 32 + (t & 31);     // [0, 4096)

    float2 x[32];
    #pragma unroll
    for (int jb = 0; jb < 2; ++jb)
        #pragma unroll
        for (int jc = 0; jc < 2; ++jc) {
            const int j3 = 4 * h + 2 * jb + jc;
            #pragma unroll
            for (int i3 = 0; i3 < 8; ++i3)
                x[jb * 16 + jc * 8 + i3] =
                    in[(size_t)((r3 * 8 + j3) * 64 + c3 * 8 + i3) * 4096 + s];
        }

    qmt_stage_cb_half(x, Mre, Mim);

    STAGE_A_COEFFS
    const size_t ob = ((size_t)(r3 * 8 + c3) * 64) * 4096 + s;
    #pragma unroll
    for (int sbH = 0; sbH < 2; ++sbH)
        #pragma unroll
        for (int sc = 0; sc < 4; ++sc)
            #pragma unroll
            for (int sbL = 0; sbL < 2; ++sbL) {
                const int q = sbH * 16 + sc * 4 + sbL;
                const float2 o0 = x[q], o1 = x[q + 2];
                float2 r0, r1;
                r0.x = __shfl_xor(o0.x, 32); r0.y = __shfl_xor(o0.y, 32);
                r1.x = __shfl_xor(o1.x, 32); r1.y = __shfl_xor(o1.y, 32);
                const int sb = sbH * 2 + sbL;
                #pragma unroll
                for (int sal = 0; sal < 2; ++sal) {
                    const float re = Are[sal][0] * o0.x - Aim[sal][0] * o0.y
                                   + Are[sal][1] * o1.x - Aim[sal][1] * o1.y
                                   + Bre[sal][0] * r0.x - Bim[sal][0] * r0.y
                                   + Bre[sal][1] * r1.x - Bim[sal][1] * r1.y;
                    const float im = Are[sal][0] * o0.y + Aim[sal][0] * o0.x
                                   + Are[sal][1] * o1.y + Aim[sal][1] * o1.x
                                   + Bre[sal][0] * r0.y + Bim[sal][0] * r0.x
                                   + Bre[sal][1] * r1.y + Bim[sal][1] * r1.x;
                    const int s3 = (2 * h + sal) * 16 + sb * 4 + sc;
                    out[ob + (size_t)s3 * 4096] = make_float2(re, im);
                }
            }
}

// ---------------------------------------------------------------------------
// Pass C (= p4, MSB triplet), r12: real-only out [s_hi, s3(64), s_lo(32)].
// 2048 blocks x 256 threads.
// ---------------------------------------------------------------------------
__global__ __launch_bounds__(256) void qmt_p4(const float2* __restrict__ in,
                                              float* __restrict__ out,
                                              const float* __restrict__ Mre,
                                              const float* __restrict__ Mim)
{
    const int t = threadIdx.x;
    const int h = (t >> 5) & 1;
    const int s = (blockIdx.x * 4 + (t >> 6)) * 32 + (t & 31);   // [0, 2^18)

    float2 x[32];
    #pragma unroll
    for (int jb = 0; jb < 2; ++jb)
        #pragma unroll
        for (int jc = 0; jc < 2; ++jc) {
            const int j3 = 4 * h + 2 * jb + jc;
            #pragma unroll
            for (int i3 = 0; i3 < 8; ++i3)
                x[jb * 16 + jc * 8 + i3] = in[(size_t)(j3 * 8 + i3) * 262144 + s];
        }

    qmt_stage_cb_half(x, Mre, Mim);

    STAGE_A_COEFFS
    const size_t ob = (size_t)(s >> 5) * 2048 + (s & 31);
    #pragma unroll
    for (int sbH = 0; sbH < 2; ++sbH)
        #pragma unroll
        for (int sc = 0; sc < 4; ++sc)
            #pragma unroll
            for (int sbL = 0; sbL < 2; ++sbL) {
                const int q = sbH * 16 + sc * 4 + sbL;
                const float2 o0 = x[q], o1 = x[q + 2];
                float2 r0, r1;
                r0.x = __shfl_xor(o0.x, 32); r0.y = __shfl_xor(o0.y, 32);
                r1.x = __shfl_xor(o1.x, 32); r1.y = __shfl_xor(o1.y, 32);
                const int sb = sbH * 2 + sbL;
                #pragma unroll
                for (int sal = 0; sal < 2; ++sal) {
                    const float re = Are[sal][0] * o0.x - Aim[sal][0] * o0.y
                                   + Are[sal][1] * o1.x - Aim[sal][1] * o1.y
                                   + Bre[sal][0] * r0.x - Bim[sal][0] * r0.y
                                   + Bre[sal][1] * r1.x - Bim[sal][1] * r1.y;
                    const int s3 = (2 * h + sal) * 16 + sb * 4 + sc;
                    out[ob + (size_t)s3 * 32] = re;
                }
            }
}

// ---------------------------------------------------------------------------
__global__ void gather_idx(const float* __restrict__ P, const int* __restrict__ idxs,
                           float* __restrict__ out, const int n)
{
    const int i = blockIdx.x * 256 + threadIdx.x;
    if (i < n) {
        const int idx = idxs[i];
        const int s = idx & 262143;
        const size_t pos = (size_t)(s >> 5) * 2048 + (size_t)(idx >> 18) * 32 + (s & 31);
        out[i] = P[pos] * g_inv_tr[0];
    }
}

// ---------------------------------------------------------------------------
extern "C" void kernel_launch(void* const* d_in, const int* in_sizes, int n_in,
                              void* d_out, int out_size, void* d_ws, size_t ws_size,
                              hipStream_t stream)
{
    const float* params = (const float*)d_in[0];  // (2, D, RANK) fp32
    const float* Mre    = (const float*)d_in[1];
    const float* Mim    = (const float*)d_in[2];
    const int*   idxs   = (const int*)d_in[3];
    float*       out    = (float*)d_out;

    float* ws = (float*)d_ws;
    float2* A  = (float2*)ws;                 // 134 MB plane
    float2* Bp = (float2*)(ws + 2 * NTOT);    // 134 MB plane
    char* Wh = (char*)Bp;
    char* Wl = Wh + (size_t)D * 2048;

    convert_w_i8<<<1024, 256, 0, stream>>>(params, Mre, Mim, Wh, Wl);
    gemm_rho_i8<<<2080, 256, 0, stream>>>(Wh, Wl, A);
    trace_inv<<<1, 256, 0, stream>>>(A);

    qmt_pAh<<<2080, 256, 0, stream>>>(A, Bp, Mre, Mim);  // 6 LSB qubits, triangle
    qmt_p3<<<2048, 256, 0, stream>>>(Bp, A, Mre, Mim);   // 3 qubits, half-split
    qmt_p4<<<2048, 256, 0, stream>>>(A, (float*)Bp, Mre, Mim);  // 3 qubits, real out

    gather_idx<<<(out_size + 255) / 256, 256, 0, stream>>>((float*)Bp, idxs, out, out_size);
}

// Round 10
// 366.184 us; speedup vs baseline: 1.1674x; 1.0806x over previous
//
#include <hip/hip_runtime.h>

#define D 4096
#define RANK 1024
#define UELEMS 4194304ULL   // D*RANK
#define NTOT 16777216ULL    // 4^12 = D*D
#define QSCALE 16000.0f

typedef __attribute__((ext_vector_type(4))) int i32x4;

__device__ float g_inv_tr[1];
__device__ float g_scale[D];
__device__ float g_mdre[16];   // M-dagger tables: M†[s][i][j] = conj(M[s][j][i])
__device__ float g_mdim[16];

static __device__ __forceinline__ void load_lds16(const void* g, void* l) {
    __builtin_amdgcn_global_load_lds(
        (const __attribute__((address_space(1))) unsigned int*)g,
        (__attribute__((address_space(3))) unsigned int*)l, 16, 0, 0);
}

#define MFMA_I8 __builtin_amdgcn_mfma_i32_16x16x64_i8

// ---------------------------------------------------------------------------
// i8 split quantization of W = [Ur | Ui] with per-row scale (verified r6).
// ---------------------------------------------------------------------------
__global__ __launch_bounds__(256) void convert_w_i8(const float* __restrict__ P,
                                                    const float* __restrict__ Mre,
                                                    const float* __restrict__ Mim,
                                                    char* __restrict__ Wh,
                                                    char* __restrict__ Wl)
{
    if (blockIdx.x == 0 && threadIdx.x < 16) {
        const int s = threadIdx.x >> 2, i = (threadIdx.x >> 1) & 1, j = threadIdx.x & 1;
        g_mdre[threadIdx.x] =  Mre[s * 4 + j * 2 + i];
        g_mdim[threadIdx.x] = -Mim[s * 4 + j * 2 + i];
    }

    const int w = threadIdx.x >> 6, lane = threadIdx.x & 63;
    const int row = blockIdx.x * 4 + w;

    float ur[16], ui[16];
    const float* pr = P + (size_t)row * RANK + lane * 16;
    const float* pi = P + UELEMS + (size_t)row * RANK + lane * 16;
    #pragma unroll
    for (int q = 0; q < 4; ++q) {
        const float4 a = ((const float4*)pr)[q];
        const float4 b = ((const float4*)pi)[q];
        ur[q * 4 + 0] = a.x; ur[q * 4 + 1] = a.y; ur[q * 4 + 2] = a.z; ur[q * 4 + 3] = a.w;
        ui[q * 4 + 0] = b.x; ui[q * 4 + 1] = b.y; ui[q * 4 + 2] = b.z; ui[q * 4 + 3] = b.w;
    }
    float mx = 0.f;
    #pragma unroll
    for (int e = 0; e < 16; ++e)
        mx = fmaxf(mx, fmaxf(fabsf(ur[e]), fabsf(ui[e])));
    #pragma unroll
    for (int off = 1; off < 64; off <<= 1)
        mx = fmaxf(mx, __shfl_xor(mx, off));
    const float inv = mx > 0.f ? QSCALE / mx : 0.f;
    if (lane == 0) g_scale[row] = mx / QSCALE;

    int hr[16], lr[16], hi[16], li[16];
    #pragma unroll
    for (int e = 0; e < 16; ++e) {
        float q = ur[e] * inv;
        float hf = rintf(q * 0.0078125f);
        hr[e] = (int)hf; lr[e] = (int)rintf(q - 128.f * hf);
        q = ui[e] * inv;
        hf = rintf(q * 0.0078125f);
        hi[e] = (int)hf; li[e] = (int)rintf(q - 128.f * hf);
    }
    uint4 phr, plr, phi, pli;
    unsigned* dst[4] = {(unsigned*)&phr, (unsigned*)&plr, (unsigned*)&phi, (unsigned*)&pli};
    #pragma unroll
    for (int q = 0; q < 4; ++q) {
        unsigned a = 0, b = 0, c = 0, d = 0;
        #pragma unroll
        for (int k = 0; k < 4; ++k) {
            const int sh = k * 8;
            a |= (unsigned)(hr[q * 4 + k] & 255) << sh;
            b |= (unsigned)(lr[q * 4 + k] & 255) << sh;
            c |= (unsigned)(hi[q * 4 + k] & 255) << sh;
            d |= (unsigned)(li[q * 4 + k] & 255) << sh;
        }
        dst[0][q] = a; dst[1][q] = b; dst[2][q] = c; dst[3][q] = d;
    }
    const size_t b1 = (size_t)row * 2048 + lane * 16;
    *(uint4*)&Wh[b1] = phr;          *(uint4*)&Wl[b1] = plr;
    *(uint4*)&Wh[b1 + 1024] = phi;   *(uint4*)&Wl[b1 + 1024] = pli;
}

// ---------------------------------------------------------------------------
// Fused Hermitian GEMM in i8 (r14+swizzle, verified 123 µs; 6-variant ledger
// brackets this decomposition at 123-141 -> plateaued, kept verbatim).
// ---------------------------------------------------------------------------
__global__ __launch_bounds__(256, 2) void gemm_rho_i8(const char* __restrict__ Wh,
                                                      const char* __restrict__ Wl,
                                                      float2* __restrict__ rho)
{
    __shared__ __align__(16) char sA[2][4][64 * 64];   // 32768 B
    __shared__ __align__(16) char sB[2][4][64 * 64];   // 32768 B

    const int g0 = blockIdx.x;
    const int g = (g0 & 7) * 260 + (g0 >> 3);

    int bi = (int)((sqrtf(8.f * (float)g + 1.f) - 1.f) * 0.5f);
    while (bi * (bi + 1) / 2 > g) --bi;
    while ((bi + 1) * (bi + 2) / 2 <= g) ++bi;
    const int bj = g - bi * (bi + 1) / 2;
    const int row0 = bi << 6, col0 = bj << 6;

    const int t = threadIdx.x;
    const int lane = t & 63, w = t >> 6;
    const int wr = w >> 1, wc = w & 1;          // 2x2 waves of 32x32

    const int ra = t >> 2;
    const int kca = (t & 3) ^ ((ra >> 1) & 3);  // xor-swizzled k-slot
    const size_t aoff = (size_t)(row0 + ra) * 2048 + kca * 16;
    const size_t boff = (size_t)(col0 + ra) * 2048 + kca * 16;
    const int ldso = t * 16;

    const int m = lane & 15, gq = lane >> 4;
    const int fko = (gq ^ ((m >> 1) & 3)) * 16;

    i32x4 rehh[2][2], remx[2][2], iphh[2][2], ipmx[2][2], iqhh[2][2], iqmx[2][2];
    #pragma unroll
    for (int i = 0; i < 2; ++i)
        #pragma unroll
        for (int j = 0; j < 2; ++j) {
            rehh[i][j] = (i32x4){0, 0, 0, 0}; remx[i][j] = (i32x4){0, 0, 0, 0};
            iphh[i][j] = (i32x4){0, 0, 0, 0}; ipmx[i][j] = (i32x4){0, 0, 0, 0};
            iqhh[i][j] = (i32x4){0, 0, 0, 0}; iqmx[i][j] = (i32x4){0, 0, 0, 0};
        }

    char* const sA0 = &sA[0][0][0];
    char* const sB0 = &sB[0][0][0];

    load_lds16(Wh + aoff,        sA0 + ldso);
    load_lds16(Wl + aoff,        sA0 + 4096  + ldso);
    load_lds16(Wh + aoff + 1024, sA0 + 8192  + ldso);
    load_lds16(Wl + aoff + 1024, sA0 + 12288 + ldso);
    load_lds16(Wh + boff,        sB0 + ldso);
    load_lds16(Wl + boff,        sB0 + 4096  + ldso);
    load_lds16(Wh + boff + 1024, sB0 + 8192  + ldso);
    load_lds16(Wl + boff + 1024, sB0 + 12288 + ldso);
    __syncthreads();

#define DO_MFMA_J(j)                                                          \
    _Pragma("unroll")                                                         \
    for (int i = 0; i < 2; ++i) {                                             \
        i32x4 r;                                                              \
        r = rehh[i][j];                                                       \
        r = MFMA_I8(fa1h[i], b1h[j], r, 0, 0, 0);                             \
        r = MFMA_I8(fa2h[i], b2h[j], r, 0, 0, 0);                             \
        rehh[i][j] = r;                                                       \
        r = remx[i][j];                                                       \
        r = MFMA_I8(fa1h[i], b1l[j], r, 0, 0, 0);                             \
        r = MFMA_I8(fa1l[i], b1h[j], r, 0, 0, 0);                             \
        r = MFMA_I8(fa2h[i], b2l[j], r, 0, 0, 0);                             \
        r = MFMA_I8(fa2l[i], b2h[j], r, 0, 0, 0);                             \
        remx[i][j] = r;                                                       \
        r = MFMA_I8(fa2h[i], b1h[j], iphh[i][j], 0, 0, 0); iphh[i][j] = r;    \
        r = ipmx[i][j];                                                       \
        r = MFMA_I8(fa2h[i], b1l[j], r, 0, 0, 0);                             \
        r = MFMA_I8(fa2l[i], b1h[j], r, 0, 0, 0);                             \
        ipmx[i][j] = r;                                                       \
        r = MFMA_I8(fa1h[i], b2h[j], iqhh[i][j], 0, 0, 0); iqhh[i][j] = r;    \
        r = iqmx[i][j];                                                       \
        r = MFMA_I8(fa1h[i], b2l[j], r, 0, 0, 0);                             \
        r = MFMA_I8(fa1l[i], b2h[j], r, 0, 0, 0);                             \
        iqmx[i][j] = r;                                                       \
    }

    #pragma unroll 2
    for (int kt = 0; kt < 16; ++kt) {
        const int cur = kt & 1;
        const char* sAc = sA0 + cur * 16384;
        const char* sBc = sB0 + cur * 16384;
        char* sAn = sA0 + (cur ^ 1) * 16384;
        char* sBn = sB0 + (cur ^ 1) * 16384;
        const size_t ko = (size_t)(kt + 1) * 64;

        if (kt < 15) {
            load_lds16(Wh + aoff + ko,        sAn + ldso);
            load_lds16(Wl + aoff + ko,        sAn + 4096  + ldso);
            load_lds16(Wh + aoff + ko + 1024, sAn + 8192  + ldso);
            load_lds16(Wl + aoff + ko + 1024, sAn + 12288 + ldso);
            load_lds16(Wh + boff + ko,        sBn + ldso);
            load_lds16(Wl + boff + ko,        sBn + 4096  + ldso);
            load_lds16(Wh + boff + ko + 1024, sBn + 8192  + ldso);
            load_lds16(Wl + boff + ko + 1024, sBn + 12288 + ldso);
        }

        i32x4 fa1h[2], fa1l[2], fa2h[2], fa2l[2];
        i32x4 b1h[2], b1l[2], b2h[2], b2l[2];
        #pragma unroll
        for (int i = 0; i < 2; ++i) {
            const int off = (wr * 32 + i * 16 + m) * 64 + fko;
            fa1h[i] = *(const i32x4*)(sAc + off);
            fa1l[i] = *(const i32x4*)(sAc + 4096  + off);
            fa2h[i] = *(const i32x4*)(sAc + 8192  + off);
            fa2l[i] = *(const i32x4*)(sAc + 12288 + off);
        }
        #pragma unroll
        for (int j = 0; j < 2; ++j) {
            const int off = (wc * 32 + j * 16 + m) * 64 + fko;
            b1h[j] = *(const i32x4*)(sBc + off);
            b1l[j] = *(const i32x4*)(sBc + 4096  + off);
            b2h[j] = *(const i32x4*)(sBc + 8192  + off);
            b2l[j] = *(const i32x4*)(sBc + 12288 + off);
        }

        __builtin_amdgcn_s_setprio(1);
        DO_MFMA_J(0)
        DO_MFMA_J(1)
        __builtin_amdgcn_s_setprio(0);

        __syncthreads();
    }
#undef DO_MFMA_J

    #pragma unroll
    for (int j = 0; j < 2; ++j) {
        const int col = col0 + wc * 32 + j * 16 + m;
        const float sc = g_scale[col];
        const int c64 = col >> 6;
        #pragma unroll
        for (int i = 0; i < 2; ++i) {
            #pragma unroll
            for (int r = 0; r < 4; ++r) {
                const int row = row0 + wr * 32 + i * 16 + gq * 4 + r;
                const float s2 = g_scale[row] * sc;
                const float re = s2 * (16384.f * (float)rehh[i][j][r] + 128.f * (float)remx[i][j][r]);
                const float im = s2 * (16384.f * (float)(iphh[i][j][r] - iqhh[i][j][r])
                                      + 128.f * (float)(ipmx[i][j][r] - iqmx[i][j][r]));
                const int r64 = row >> 6;
                if (r64 > c64 || row >= col) rho[(size_t)row * D + col] = make_float2(re, im);
                if (r64 == c64 && row > col) rho[(size_t)col * D + row] = make_float2(re, -im);
            }
        }
    }
}

// ---------------------------------------------------------------------------
__global__ void trace_inv(const float2* __restrict__ rho)
{
    __shared__ float red[256];
    float s = 0.f;
    for (int d = threadIdx.x; d < D; d += 256)
        s += rho[(size_t)d * (D + 1)].x;
    red[threadIdx.x] = s;
    __syncthreads();
    for (int off = 128; off > 0; off >>= 1) {
        if (threadIdx.x < off) red[threadIdx.x] += red[threadIdx.x + off];
        __syncthreads();
    }
    if (threadIdx.x == 0) g_inv_tr[0] = 1.0f / red[0];
}

// ---------------------------------------------------------------------------
// 2-qubit staged contraction on a 4x4 register tile (verified r9).
// ---------------------------------------------------------------------------
static __device__ __forceinline__ void qmt2(float2* x,
                                            const float* __restrict__ Mre,
                                            const float* __restrict__ Mim)
{
    float2 y[16];
    #pragma unroll
    for (int sb = 0; sb < 4; ++sb)
        #pragma unroll
        for (int ja = 0; ja < 2; ++ja)
            #pragma unroll
            for (int ia = 0; ia < 2; ++ia) {
                float2 acc = make_float2(0.f, 0.f);
                #pragma unroll
                for (int ib = 0; ib < 2; ++ib)
                    #pragma unroll
                    for (int jb = 0; jb < 2; ++jb) {
                        const float mr = Mre[sb * 4 + ib * 2 + jb];
                        const float mi = Mim[sb * 4 + ib * 2 + jb];
                        const float2 v = x[(ja * 2 + jb) * 4 + ia * 2 + ib];
                        acc.x += mr * v.x - mi * v.y;
                        acc.y += mr * v.y + mi * v.x;
                    }
                y[sb * 4 + ja * 2 + ia] = acc;
            }
    #pragma unroll
    for (int sa = 0; sa < 4; ++sa)
        #pragma unroll
        for (int sb = 0; sb < 4; ++sb) {
            float2 acc = make_float2(0.f, 0.f);
            #pragma unroll
            for (int ia = 0; ia < 2; ++ia)
                #pragma unroll
                for (int ja = 0; ja < 2; ++ja) {
                    const float mr = Mre[sa * 4 + ia * 2 + ja];
                    const float mi = Mim[sa * 4 + ia * 2 + ja];
                    const float2 v = y[sb * 4 + ja * 2 + ia];
                    acc.x += mr * v.x - mi * v.y;
                    acc.y += mr * v.y + mi * v.x;
                }
            x[sa * 4 + sb] = acc;
        }
}

// ---------------------------------------------------------------------------
// The 3-stage 6-qubit pipeline (2 LDS exchanges), verified in pAh. Input:
// x[j2*4+i2] = T[row = a4*4+j2][col = t4*4+i2] for thread t=(a4<<4)|t4.
// Output: x[dd] = outcome (dd*256 + t), dd in [0,16). Caller syncs before
// reusing X.
// ---------------------------------------------------------------------------
static __device__ __forceinline__ void pA_pipeline(float2* x, float2* X, const int t,
                                                   const float* __restrict__ mre,
                                                   const float* __restrict__ mim)
{
    qmt2(x, mre, mim);
    #pragma unroll
    for (int d = 0; d < 16; ++d) X[t * 17 + d] = x[d];
    __syncthreads();
    const int a2 = t >> 6, t2 = (t >> 4) & 3, d1 = t & 15;
    #pragma unroll
    for (int j2 = 0; j2 < 4; ++j2)
        #pragma unroll
        for (int i2 = 0; i2 < 4; ++i2)
            x[j2 * 4 + i2] = X[((a2 * 4 + j2) * 16 + t2 * 4 + i2) * 17 + d1];
    __syncthreads();
    qmt2(x, mre, mim);
    #pragma unroll
    for (int d = 0; d < 16; ++d) X[(a2 * 4 + t2) * 257 + d * 16 + d1] = x[d];
    __syncthreads();
    const int e2 = t >> 4, e1 = t & 15;
    #pragma unroll
    for (int j2 = 0; j2 < 4; ++j2)
        #pragma unroll
        for (int i2 = 0; i2 < 4; ++i2)
            x[j2 * 4 + i2] = X[(j2 * 4 + i2) * 257 + e2 * 16 + e1];
    qmt2(x, mre, mim);
}

// ---------------------------------------------------------------------------
// Fused pass A, Hermitian (r10 compute). r19: output layout changed to
// [o_hi(256)][rc(4096)][o_lo(16)] (o = outcome = dd*256 + t, o_hi = o>>4 =
// dd*16 + (t>>4), o_lo = t&15) so the fused p34 can read all rc for a fixed
// outcome. Writes stay line-aligned: 16 consecutive lanes x 8 B = 128-B
// aligned segments (rc fixed per block, o_lo = t&15 contiguous).
// ---------------------------------------------------------------------------
__global__ __launch_bounds__(256) void qmt_pAh(const float2* __restrict__ in,
                                               float2* __restrict__ out,
                                               const float* __restrict__ Mre,
                                               const float* __restrict__ Mim)
{
    __shared__ __align__(16) float2 X[256 * 17];   // 34816 B
    const int t = threadIdx.x;
    const int g = blockIdx.x;
    int rr = (int)((sqrtf(8.f * (float)g + 1.f) - 1.f) * 0.5f);
    while (rr * (rr + 1) / 2 > g) --rr;
    while ((rr + 1) * (rr + 2) / 2 <= g) ++rr;
    const int cc = g - rr * (rr + 1) / 2;          // cc <= rr

    const int a4 = t >> 4, t4 = t & 15;
    float2 x0[16], x[16];
    #pragma unroll
    for (int j2 = 0; j2 < 4; ++j2) {
        const float2* p = in + ((size_t)(rr * 64 + a4 * 4 + j2)) * 4096 + cc * 64 + t4 * 4;
        const float4 v0 = ((const float4*)p)[0];
        const float4 v1 = ((const float4*)p)[1];
        x0[j2 * 4 + 0] = make_float2(v0.x, v0.y);
        x0[j2 * 4 + 1] = make_float2(v0.z, v0.w);
        x0[j2 * 4 + 2] = make_float2(v1.x, v1.y);
        x0[j2 * 4 + 3] = make_float2(v1.z, v1.w);
    }

    const size_t wbase = (size_t)(t >> 4) * 65536 + (t & 15);

    // pass 0: M, tile (rr,cc)
    #pragma unroll
    for (int q = 0; q < 16; ++q) x[q] = x0[q];
    pA_pipeline(x, X, t, Mre, Mim);
    {
        const size_t rc0 = (size_t)(rr * 64 + cc) * 16;
        #pragma unroll
        for (int d = 0; d < 16; ++d)
            out[(size_t)d * 1048576 + wbase + rc0] = x[d];
    }

    // pass 1: M-dagger + conjugate, tile (cc,rr)
    if (rr != cc) {
        __syncthreads();
        #pragma unroll
        for (int q = 0; q < 16; ++q) x[q] = x0[q];
        pA_pipeline(x, X, t, g_mdre, g_mdim);
        const size_t rc1 = (size_t)(cc * 64 + rr) * 16;
        #pragma unroll
        for (int d = 0; d < 16; ++d)
            out[(size_t)d * 1048576 + wbase + rc1] = make_float2(x[d].x, -x[d].y);
    }
}

// ---------------------------------------------------------------------------
// r19: fused pass B+C — one 6-qubit contraction over (rr,cc) per LSB-outcome
// batch d34 (replaces qmt_p3 + qmt_p4; saves the 268 MB materialize/reread).
// Reads in[o_hi*65536 + rc*16 + o_lo] (o_hi = d34>>4, o_lo = d34&15): 8-B
// loads at 128-B stride; the 16 sibling blocks sharing o_hi read the same
// lines -> L2-served. Swizzle d34=(b&7)*512+(b>>3) puts each sibling group on
// one XCD, launched consecutively (512 KB working set << 4 MB L2).
// Output: out[d34*4096 + outcome] real, coalesced. Final P index:
// idx = [o34 (6 qubits, s1..s6)][d34 (6 qubits, s7..s12)] -> gather pos =
// (idx & 4095)*4096 + (idx>>12).
// ---------------------------------------------------------------------------
__global__ __launch_bounds__(256) void qmt_p34(const float2* __restrict__ in,
                                               float* __restrict__ out,
                                               const float* __restrict__ Mre,
                                               const float* __restrict__ Mim)
{
    __shared__ __align__(16) float2 X[256 * 17];   // 34816 B
    const int t = threadIdx.x;
    const int b = blockIdx.x;
    const int d34 = (b & 7) * 512 + (b >> 3);      // XCD-grouped batch
    const int ohi = d34 >> 4, olo = d34 & 15;

    const float2* base = in + (size_t)ohi * 65536 + olo;
    const int a4 = t >> 4, t4 = t & 15;
    float2 x[16];
    #pragma unroll
    for (int j2 = 0; j2 < 4; ++j2) {
        const int rcr = (a4 * 4 + j2) * 64 + t4 * 4;
        #pragma unroll
        for (int i2 = 0; i2 < 4; ++i2)
            x[j2 * 4 + i2] = base[(size_t)(rcr + i2) * 16];
    }

    pA_pipeline(x, X, t, Mre, Mim);

    const size_t ob = (size_t)d34 * 4096 + t;
    #pragma unroll
    for (int d = 0; d < 16; ++d)
        out[ob + (size_t)d * 256] = x[d].x;
}

// ---------------------------------------------------------------------------
__global__ void gather_idx(const float* __restrict__ P, const int* __restrict__ idxs,
                           float* __restrict__ out, const int n)
{
    const int i = blockIdx.x * 256 + threadIdx.x;
    if (i < n) {
        const int idx = idxs[i];
        const size_t pos = (size_t)(idx & 4095) * 4096 + (idx >> 12);
        out[i] = P[pos] * g_inv_tr[0];
    }
}

// ---------------------------------------------------------------------------
extern "C" void kernel_launch(void* const* d_in, const int* in_sizes, int n_in,
                              void* d_out, int out_size, void* d_ws, size_t ws_size,
                              hipStream_t stream)
{
    const float* params = (const float*)d_in[0];  // (2, D, RANK) fp32
    const float* Mre    = (const float*)d_in[1];
    const float* Mim    = (const float*)d_in[2];
    const int*   idxs   = (const int*)d_in[3];
    float*       out    = (float*)d_out;

    float* ws = (float*)d_ws;
    float2* A  = (float2*)ws;                 // 134 MB plane
    float2* Bp = (float2*)(ws + 2 * NTOT);    // 134 MB plane
    char* Wh = (char*)Bp;                     // dead after gemm
    char* Wl = Wh + (size_t)D * 2048;

    convert_w_i8<<<1024, 256, 0, stream>>>(params, Mre, Mim, Wh, Wl);
    gemm_rho_i8<<<2080, 256, 0, stream>>>(Wh, Wl, A);
    trace_inv<<<1, 256, 0, stream>>>(A);

    qmt_pAh<<<2080, 256, 0, stream>>>(A, Bp, Mre, Mim);  // 6 LSB qubits -> [o_hi][rc][o_lo]
    qmt_p34<<<4096, 256, 0, stream>>>(Bp, (float*)A, Mre, Mim);  // 6 MSB qubits, real out

    gather_idx<<<(out_size + 255) / 256, 256, 0, stream>>>((float*)A, idxs, out, out_size);
}